// Round 3
// baseline (57.385 us; speedup 1.0000x reference)
//
#include <hip/hip_runtime.h>

constexpr int C   = 640;
constexpr int HW  = 25;
constexpr int CHALF = 320;       // channels per gram block
constexpr int PAD = 164;         // LDS row stride in floats (bank-spread for u0 in {0,5,10,15,20})
constexpr int PSTRIDE = 832;     // ws floats per gram block: 625 G + 200 moments (+pad)
constexpr int WSTRIDE = 704;     // ws floats per sample in sink region: 625 sim + 25 a + 25 b

__device__ __forceinline__ float rl(float x, int lane) {
  return __uint_as_float(__builtin_amdgcn_readlane(__float_as_uint(x), lane));
}

// ---------- Kernel 1: partial Gram (320 channels) + partial moments ----------
__device__ __forceinline__ void scatter8(const float4* r, int tid, float* st) {
  // st = [2][25][PAD]; chunk = 160 ch -> 1000 float4 per matrix, 2000 total
  #pragma unroll
  for (int p = 0; p < 8; ++p) {
    int idx = tid + p * 256;
    if (idx < 2000) {
      int mat = (idx < 1000) ? 0 : 1;
      int e = 4 * (idx - mat * 1000);     // element within chunk-matrix [0,4000)
      int c = e / 25, k = e - 25 * c;     // channel, hw
      float* mb = st + mat * (HW * PAD);
      float v0 = r[p].x, v1 = r[p].y, v2 = r[p].z, v3 = r[p].w;
      mb[k * PAD + c] = v0; ++k; if (k == 25) { k = 0; ++c; }
      mb[k * PAD + c] = v1; ++k; if (k == 25) { k = 0; ++c; }
      mb[k * PAD + c] = v2; ++k; if (k == 25) { k = 0; ++c; }
      mb[k * PAD + c] = v3;
    }
  }
}

__device__ __forceinline__ void compute_chunk(const float* st, int tid, int grp, int u0, int v0,
                                              float acc[5][5], float& csum, float& csum2,
                                              int msplit, int mmat, int mrow) {
  if (tid < 250) {
    const float* qb = st + u0 * PAD + grp * 16;
    const float* sb = st + (HW * PAD) + v0 * PAD + grp * 16;
    #pragma unroll
    for (int cc4 = 0; cc4 < 4; ++cc4) {
      float4 q[5], s[5];
      #pragma unroll
      for (int i = 0; i < 5; ++i) q[i] = *reinterpret_cast<const float4*>(qb + i * PAD + cc4 * 4);
      #pragma unroll
      for (int j = 0; j < 5; ++j) s[j] = *reinterpret_cast<const float4*>(sb + j * PAD + cc4 * 4);
      #pragma unroll
      for (int i = 0; i < 5; ++i)
        #pragma unroll
        for (int j = 0; j < 5; ++j) {
          acc[i][j] = fmaf(q[i].x, s[j].x, acc[i][j]);
          acc[i][j] = fmaf(q[i].y, s[j].y, acc[i][j]);
          acc[i][j] = fmaf(q[i].z, s[j].z, acc[i][j]);
          acc[i][j] = fmaf(q[i].w, s[j].w, acc[i][j]);
        }
    }
  }
  if (tid < 100) {   // row (=global column) moments: 2 mats x 25 rows x 2 channel-splits
    const float* mb = st + mmat * (HW * PAD) + mrow * PAD + msplit * 80;
    #pragma unroll
    for (int j4 = 0; j4 < 20; ++j4) {
      float4 v = *reinterpret_cast<const float4*>(mb + j4 * 4);
      csum += (v.x + v.y) + (v.z + v.w);
      csum2 = fmaf(v.x, v.x, csum2); csum2 = fmaf(v.y, v.y, csum2);
      csum2 = fmaf(v.z, v.z, csum2); csum2 = fmaf(v.w, v.w, csum2);
    }
  }
}

__global__ __launch_bounds__(256, 4) void emd_gram(
    const float* __restrict__ support, const float* __restrict__ query,
    float* __restrict__ part)
{
  const int bid = blockIdx.x;
  const int n = bid >> 1, h = bid & 1;
  const int tid = threadIdx.x;

  __shared__ union alignas(16) {
    float st[2 * HW * PAD];   // 32800 B staging (transposed [mat][hw][ch])
    float Gp[10 * 625];       // 25000 B partial-Gram alias
  } sa;

  const size_t base = (size_t)n * (C * HW) + (size_t)h * (CHALF * HW);
  const float4* Qg = reinterpret_cast<const float4*>(query + base);
  const float4* Sg = reinterpret_cast<const float4*>(support + base);

  float acc[5][5] = {{0.f}};
  const int tile = tid % 25, grp = tid / 25;
  const int u0 = (tile / 5) * 5, v0 = (tile % 5) * 5;
  const int msplit = tid / 50, mr = tid % 50, mmat = mr / 25, mrow = mr % 25;
  float csum = 0.f, csum2 = 0.f;

  float4 r[8];

  // load + scatter chunk 0
  #pragma unroll
  for (int p = 0; p < 8; ++p) {
    int idx = tid + p * 256;
    if (idx < 2000) r[p] = (idx < 1000) ? Qg[idx] : Sg[idx - 1000];
  }
  scatter8(r, tid, sa.st);
  __syncthreads();

  // issue chunk-1 loads early (hide HBM under chunk-0 compute)
  #pragma unroll
  for (int p = 0; p < 8; ++p) {
    int idx = tid + p * 256;
    if (idx < 2000) r[p] = (idx < 1000) ? Qg[1000 + idx] : Sg[1000 + idx - 1000];
  }
  compute_chunk(sa.st, tid, grp, u0, v0, acc, csum, csum2, msplit, mmat, mrow);
  __syncthreads();

  scatter8(r, tid, sa.st);
  __syncthreads();

  compute_chunk(sa.st, tid, grp, u0, v0, acc, csum, csum2, msplit, mmat, mrow);
  __syncthreads();   // staging reads done; safe to alias Gp

  if (tid < 250) {
    #pragma unroll
    for (int i = 0; i < 5; ++i)
      #pragma unroll
      for (int j = 0; j < 5; ++j)
        sa.Gp[grp * 625 + (u0 + i) * 25 + (v0 + j)] = acc[i][j];
  }
  __syncthreads();

  float* w = part + (size_t)bid * PSTRIDE;
  for (int p = tid; p < 625; p += 256) {
    float g = 0.f;
    #pragma unroll
    for (int gg = 0; gg < 10; ++gg) g += sa.Gp[gg * 625 + p];
    w[p] = g;
  }
  if (tid < 100) {
    int o = 625 + ((msplit * 2 + mmat) * 2) * 25 + mrow;
    w[o] = csum;
    w[o + 25] = csum2;
  }
}

// ---------- Kernel 2: combine halves -> sim + marginals ----------
__global__ __launch_bounds__(256) void emd_combine(
    const float* __restrict__ part, float* __restrict__ sink)
{
  const int n = blockIdx.x, tid = threadIdx.x;
  const float* p0 = part + (size_t)(2 * n) * PSTRIDE;
  const float* p1 = part + (size_t)(2 * n + 1) * PSTRIDE;
  float* w = sink + (size_t)n * WSTRIDE;

  __shared__ float G[625];
  __shared__ float sQ[25], sS[25], ssQ[25], ssS[25];
  __shared__ float am[25], bm[25], nq[25], ns[25];
  __shared__ float scal[2];

  for (int p = tid; p < 625; p += 256) G[p] = p0[p] + p1[p];
  if (tid < 50) {
    int mat = tid / 25, row = tid % 25;
    float s = 0.f, ss = 0.f;
    #pragma unroll
    for (int split = 0; split < 2; ++split) {
      int o = 625 + ((split * 2 + mat) * 2) * 25 + row;
      s  += p0[o] + p1[o];
      ss += p0[o + 25] + p1[o + 25];
    }
    if (mat == 0) { sQ[row] = s; ssQ[row] = ss; }
    else          { sS[row] = s; ssS[row] = ss; }
  }
  __syncthreads();

  if (tid < 25) {
    float s = 0.f;
    #pragma unroll
    for (int j = 0; j < 25; ++j) s += G[tid * 25 + j];
    am[tid] = fmaxf(s * (1.f / 25.f), 0.f) + 0.001f + 1e-5f;
    float var = ssQ[tid] - sQ[tid] * sQ[tid] * (1.f / C);
    nq[tid] = fmaxf(sqrtf(fmaxf(var, 0.f)), 1e-8f);
  } else if (tid >= 32 && tid < 57) {
    int v = tid - 32;
    float s = 0.f;
    #pragma unroll
    for (int u = 0; u < 25; ++u) s += G[u * 25 + v];
    bm[v] = fmaxf(s * (1.f / 25.f), 0.f) + 0.001f + 1e-5f;
    float var = ssS[v] - sS[v] * sS[v] * (1.f / C);
    ns[v] = fmaxf(sqrtf(fmaxf(var, 0.f)), 1e-8f);
  }
  __syncthreads();
  if (tid == 0)  { float s = 0.f; for (int i = 0; i < 25; ++i) s += am[i]; scal[0] = 25.f / s; }
  if (tid == 64) { float s = 0.f; for (int i = 0; i < 25; ++i) s += bm[i]; scal[1] = 25.f / s; }
  __syncthreads();

  if (tid < 25)                    w[625 + tid]      = am[tid] * scal[0];
  else if (tid >= 32 && tid < 57)  w[650 + tid - 32] = bm[tid - 32] * scal[1];

  for (int p = tid; p < 625; p += 256) {
    int u = p / 25, v = p % 25;
    float cov = G[p] - sQ[u] * sS[v] * (1.f / C);
    w[p] = cov / (nq[u] * ns[v]);
  }
}

// ---------- Kernel 3: Sinkhorn + reduction, one wave/sample ----------
__global__ __launch_bounds__(64) void emd_sink(
    const float* __restrict__ sink, float* __restrict__ out)
{
  const int n    = blockIdx.x;
  const int lane = threadIdx.x;
  const int u    = (lane < 25) ? lane : 24;
  const float* w = sink + (size_t)n * WSTRIDE;

  float simr[25], Krow[25], Kcol[25];
  #pragma unroll
  for (int j = 0; j < 25; ++j) simr[j] = w[u * 25 + j];
  #pragma unroll
  for (int j = 0; j < 25; ++j) Kcol[j] = __expf(-20.f * (1.f - w[j * 25 + u]));
  #pragma unroll
  for (int j = 0; j < 25; ++j) Krow[j] = __expf(-20.f * (1.f - simr[j]));
  const float a_u = w[625 + u], b_u = w[650 + u];

  float vv = 1.0f, uu = 0.0f, vold = 1.0f;
  #pragma unroll 1
  for (int it = 0; it < 100; ++it) {
    float s0 = 0, s1 = 0, s2 = 0, s3 = 0, s4 = 0;
    #pragma unroll
    for (int j = 0; j < 25; j += 5) {
      s0 = fmaf(Krow[j + 0], rl(vv, j + 0), s0);
      s1 = fmaf(Krow[j + 1], rl(vv, j + 1), s1);
      s2 = fmaf(Krow[j + 2], rl(vv, j + 2), s2);
      s3 = fmaf(Krow[j + 3], rl(vv, j + 3), s3);
      s4 = fmaf(Krow[j + 4], rl(vv, j + 4), s4);
    }
    uu = a_u * __builtin_amdgcn_rcpf(((((s0 + s1) + (s2 + s3)) + s4) + 1e-30f));

    s0 = s1 = s2 = s3 = s4 = 0;
    #pragma unroll
    for (int j = 0; j < 25; j += 5) {
      s0 = fmaf(Kcol[j + 0], rl(uu, j + 0), s0);
      s1 = fmaf(Kcol[j + 1], rl(uu, j + 1), s1);
      s2 = fmaf(Kcol[j + 2], rl(uu, j + 2), s2);
      s3 = fmaf(Kcol[j + 3], rl(uu, j + 3), s3);
      s4 = fmaf(Kcol[j + 4], rl(uu, j + 4), s4);
    }
    vv = b_u * __builtin_amdgcn_rcpf(((((s0 + s1) + (s2 + s3)) + s4) + 1e-30f));

    if ((it & 7) == 7) {
      bool conv = fabsf(vv - vold) <= 1e-5f * fabsf(vv);
      if (__all(conv)) break;
      vold = vv;
    }
  }
  {
    float s0 = 0, s1 = 0, s2 = 0, s3 = 0, s4 = 0;
    #pragma unroll
    for (int j = 0; j < 25; j += 5) {
      s0 = fmaf(Krow[j + 0], rl(vv, j + 0), s0);
      s1 = fmaf(Krow[j + 1], rl(vv, j + 1), s1);
      s2 = fmaf(Krow[j + 2], rl(vv, j + 2), s2);
      s3 = fmaf(Krow[j + 3], rl(vv, j + 3), s3);
      s4 = fmaf(Krow[j + 4], rl(vv, j + 4), s4);
    }
    uu = a_u * __builtin_amdgcn_rcpf(((((s0 + s1) + (s2 + s3)) + s4) + 1e-30f));
  }

  float part = 0.f;
  if (lane < 25) {
    float t0 = 0.f;
    #pragma unroll
    for (int j = 0; j < 25; ++j)
      t0 = fmaf(simr[j] * Krow[j], rl(vv, j), t0);
    part = uu * t0;
  }
  #pragma unroll
  for (int off = 32; off; off >>= 1) part += __shfl_xor(part, off);
  if (lane == 0) out[n] = part * 0.5f;   // TEMPERATURE/hw = 12.5/25
}

extern "C" void kernel_launch(void* const* d_in, const int* in_sizes, int n_in,
                              void* d_out, int out_size, void* d_ws, size_t ws_size,
                              hipStream_t stream) {
  const float* support = (const float*)d_in[0];
  const float* query   = (const float*)d_in[1];
  float* out = (float*)d_out;
  const int N = in_sizes[0] / (C * HW);   // 600
  float* partbuf = (float*)d_ws;
  float* sinkbuf = partbuf + (size_t)(2 * N) * PSTRIDE;
  emd_gram   <<<dim3(2 * N), dim3(256), 0, stream>>>(support, query, partbuf);
  emd_combine<<<dim3(N),     dim3(256), 0, stream>>>(partbuf, sinkbuf);
  emd_sink   <<<dim3(N),     dim3(64),  0, stream>>>(sinkbuf, out);
}

// Round 4
// 38.108 us; speedup vs baseline: 1.5058x; 1.5058x over previous
//
#include <hip/hip_runtime.h>

constexpr int C   = 640;
constexpr int HW  = 25;
constexpr int PSTRIDE = 832;     // ws floats per gram block: 625 G + 100 csum + 100 csum2
constexpr int WSTRIDE = 704;     // ws floats per sample: 625 sim + 25 a + 25 b

__device__ __forceinline__ float rl(float x, int lane) {
  return __uint_as_float(__builtin_amdgcn_readlane(__float_as_uint(x), lane));
}

// ---------- Kernel 1: partial Gram (320 channels) + partial moments ----------
__global__ __launch_bounds__(256, 5) void emd_gram(
    const float* __restrict__ support, const float* __restrict__ query,
    float* __restrict__ part)
{
  const int bid = blockIdx.x;
  const int n = bid >> 1, h = bid & 1;
  const int tid = threadIdx.x;

  __shared__ union alignas(16) {
    float st[8000];           // [2 mats][160 ch][25 hw] = 32000 B
    float Gp[10 * 625];       // 25000 B partial-Gram alias
  } sa;

  const size_t base = (size_t)n * (C * HW) + (size_t)h * (320 * HW);
  const float4* Qg = reinterpret_cast<const float4*>(query + base);
  const float4* Sg = reinterpret_cast<const float4*>(support + base);

  float acc[5][5] = {{0.f}};
  const int tile = tid % 25, grp = tid / 25;          // grp 0..9 (tid<250)
  const int u0 = (tile / 5) * 5, v0 = (tile % 5) * 5;
  const int mmat = tid / 50, mhalf = (tid / 25) & 1, mcol = tid % 25; // tid<100
  float csum = 0.f, csum2 = 0.f;

  for (int ch = 0; ch < 2; ++ch) {
    __syncthreads();   // previous chunk fully consumed
    #pragma unroll
    for (int p = 0; p < 8; ++p) {
      int idx = tid + p * 256;
      if (idx < 2000) {
        float4 val = (idx < 1000) ? Qg[ch * 1000 + idx] : Sg[ch * 1000 + (idx - 1000)];
        reinterpret_cast<float4*>(sa.st)[idx] = val;
      }
    }
    __syncthreads();

    if (tid < 250) {
      const float* qb = sa.st + grp * 16 * HW;
      const float* sb = sa.st + 4000 + grp * 16 * HW;
      #pragma unroll 2
      for (int cc = 0; cc < 16; cc += 2) {
        float q0[5], q1[5], s0[5], s1[5];
        #pragma unroll
        for (int i = 0; i < 5; ++i) {
          q0[i] = qb[cc * HW + u0 + i];
          q1[i] = qb[cc * HW + HW + u0 + i];
          s0[i] = sb[cc * HW + v0 + i];
          s1[i] = sb[cc * HW + HW + v0 + i];
        }
        #pragma unroll
        for (int i = 0; i < 5; ++i)
          #pragma unroll
          for (int j = 0; j < 5; ++j) {
            acc[i][j] = fmaf(q0[i], s0[j], acc[i][j]);
            acc[i][j] = fmaf(q1[i], s1[j], acc[i][j]);
          }
      }
    }
    if (tid < 100) {   // per-column moments: 2 mats x 2 chunk-halves x 25 cols
      const float* mb = sa.st + mmat * 4000 + mhalf * 80 * HW;
      #pragma unroll 4
      for (int c = 0; c < 80; ++c) {
        float x = mb[c * HW + mcol];
        csum += x;
        csum2 = fmaf(x, x, csum2);
      }
    }
  }
  __syncthreads();   // staging reads done; safe to alias Gp

  if (tid < 250) {
    #pragma unroll
    for (int i = 0; i < 5; ++i)
      #pragma unroll
      for (int j = 0; j < 5; ++j)
        sa.Gp[grp * 625 + (u0 + i) * 25 + (v0 + j)] = acc[i][j];
  }
  __syncthreads();

  float* w = part + (size_t)bid * PSTRIDE;
  for (int p = tid; p < 625; p += 256) {
    float g = 0.f;
    #pragma unroll
    for (int gg = 0; gg < 10; ++gg) g += sa.Gp[gg * 625 + p];
    w[p] = g;
  }
  if (tid < 100) {
    w[625 + tid] = csum;     // tid = mmat*50 + mhalf*25 + mcol
    w[725 + tid] = csum2;
  }
}

// ---------- Kernel 2: combine halves -> sim + marginals ----------
__global__ __launch_bounds__(256) void emd_combine(
    const float* __restrict__ part, float* __restrict__ sink)
{
  const int n = blockIdx.x, tid = threadIdx.x;
  const float* p0 = part + (size_t)(2 * n) * PSTRIDE;
  const float* p1 = part + (size_t)(2 * n + 1) * PSTRIDE;
  float* w = sink + (size_t)n * WSTRIDE;

  __shared__ float G[625];
  __shared__ float sQ[25], sS[25], ssQ[25], ssS[25];
  __shared__ float am[25], bm[25], nq[25], ns[25];
  __shared__ float scal[2];

  for (int p = tid; p < 625; p += 256) G[p] = p0[p] + p1[p];
  if (tid < 50) {
    int mat = tid / 25, col = tid % 25;
    int o = 625 + mat * 50 + col;
    float s  = p0[o] + p0[o + 25] + p1[o] + p1[o + 25];
    float ss = p0[o + 100] + p0[o + 125] + p1[o + 100] + p1[o + 125];
    if (mat == 0) { sQ[col] = s; ssQ[col] = ss; }
    else          { sS[col] = s; ssS[col] = ss; }
  }
  __syncthreads();

  if (tid < 25) {
    float s = 0.f;
    #pragma unroll
    for (int j = 0; j < 25; ++j) s += G[tid * 25 + j];
    am[tid] = fmaxf(s * (1.f / 25.f), 0.f) + 0.001f + 1e-5f;
    float var = ssQ[tid] - sQ[tid] * sQ[tid] * (1.f / C);
    nq[tid] = fmaxf(sqrtf(fmaxf(var, 0.f)), 1e-8f);
  } else if (tid >= 32 && tid < 57) {
    int v = tid - 32;
    float s = 0.f;
    #pragma unroll
    for (int u = 0; u < 25; ++u) s += G[u * 25 + v];
    bm[v] = fmaxf(s * (1.f / 25.f), 0.f) + 0.001f + 1e-5f;
    float var = ssS[v] - sS[v] * sS[v] * (1.f / C);
    ns[v] = fmaxf(sqrtf(fmaxf(var, 0.f)), 1e-8f);
  }
  __syncthreads();
  if (tid == 0)  { float s = 0.f; for (int i = 0; i < 25; ++i) s += am[i]; scal[0] = 25.f / s; }
  if (tid == 64) { float s = 0.f; for (int i = 0; i < 25; ++i) s += bm[i]; scal[1] = 25.f / s; }
  __syncthreads();

  if (tid < 25)                    w[625 + tid]      = am[tid] * scal[0];
  else if (tid >= 32 && tid < 57)  w[650 + tid - 32] = bm[tid - 32] * scal[1];

  for (int p = tid; p < 625; p += 256) {
    int u = p / 25, v = p % 25;
    float cov = G[p] - sQ[u] * sS[v] * (1.f / C);
    w[p] = cov / (nq[u] * ns[v]);
  }
}

// ---------- Kernel 3: Sinkhorn + reduction, one wave/sample ----------
__global__ __launch_bounds__(64) void emd_sink(
    const float* __restrict__ sink, float* __restrict__ out)
{
  const int n    = blockIdx.x;
  const int lane = threadIdx.x;
  const int u    = (lane < 25) ? lane : 24;
  const float* w = sink + (size_t)n * WSTRIDE;

  float simr[25], Krow[25], Kcol[25];
  #pragma unroll
  for (int j = 0; j < 25; ++j) simr[j] = w[u * 25 + j];
  #pragma unroll
  for (int j = 0; j < 25; ++j) Kcol[j] = __expf(-20.f * (1.f - w[j * 25 + u]));
  #pragma unroll
  for (int j = 0; j < 25; ++j) Krow[j] = __expf(-20.f * (1.f - simr[j]));
  const float a_u = w[625 + u], b_u = w[650 + u];

  float vv = 1.0f, uu = 0.0f, vold = 1.0f;
  #pragma unroll 1
  for (int it = 0; it < 100; ++it) {
    float s0 = 0, s1 = 0, s2 = 0, s3 = 0, s4 = 0;
    #pragma unroll
    for (int j = 0; j < 25; j += 5) {
      s0 = fmaf(Krow[j + 0], rl(vv, j + 0), s0);
      s1 = fmaf(Krow[j + 1], rl(vv, j + 1), s1);
      s2 = fmaf(Krow[j + 2], rl(vv, j + 2), s2);
      s3 = fmaf(Krow[j + 3], rl(vv, j + 3), s3);
      s4 = fmaf(Krow[j + 4], rl(vv, j + 4), s4);
    }
    uu = a_u * __builtin_amdgcn_rcpf(((((s0 + s1) + (s2 + s3)) + s4) + 1e-30f));

    s0 = s1 = s2 = s3 = s4 = 0;
    #pragma unroll
    for (int j = 0; j < 25; j += 5) {
      s0 = fmaf(Kcol[j + 0], rl(uu, j + 0), s0);
      s1 = fmaf(Kcol[j + 1], rl(uu, j + 1), s1);
      s2 = fmaf(Kcol[j + 2], rl(uu, j + 2), s2);
      s3 = fmaf(Kcol[j + 3], rl(uu, j + 3), s3);
      s4 = fmaf(Kcol[j + 4], rl(uu, j + 4), s4);
    }
    vv = b_u * __builtin_amdgcn_rcpf(((((s0 + s1) + (s2 + s3)) + s4) + 1e-30f));

    if ((it & 7) == 7) {
      bool conv = fabsf(vv - vold) <= 1e-5f * fabsf(vv);
      if (__all(conv)) break;
      vold = vv;
    }
  }
  {
    float s0 = 0, s1 = 0, s2 = 0, s3 = 0, s4 = 0;
    #pragma unroll
    for (int j = 0; j < 25; j += 5) {
      s0 = fmaf(Krow[j + 0], rl(vv, j + 0), s0);
      s1 = fmaf(Krow[j + 1], rl(vv, j + 1), s1);
      s2 = fmaf(Krow[j + 2], rl(vv, j + 2), s2);
      s3 = fmaf(Krow[j + 3], rl(vv, j + 3), s3);
      s4 = fmaf(Krow[j + 4], rl(vv, j + 4), s4);
    }
    uu = a_u * __builtin_amdgcn_rcpf(((((s0 + s1) + (s2 + s3)) + s4) + 1e-30f));
  }

  float part = 0.f;
  if (lane < 25) {
    float t0 = 0.f;
    #pragma unroll
    for (int j = 0; j < 25; ++j)
      t0 = fmaf(simr[j] * Krow[j], rl(vv, j), t0);
    part = uu * t0;
  }
  #pragma unroll
  for (int off = 32; off; off >>= 1) part += __shfl_xor(part, off);
  if (lane == 0) out[n] = part * 0.5f;   // TEMPERATURE/hw = 12.5/25
}

extern "C" void kernel_launch(void* const* d_in, const int* in_sizes, int n_in,
                              void* d_out, int out_size, void* d_ws, size_t ws_size,
                              hipStream_t stream) {
  const float* support = (const float*)d_in[0];
  const float* query   = (const float*)d_in[1];
  float* out = (float*)d_out;
  const int N = in_sizes[0] / (C * HW);   // 600
  float* partbuf = (float*)d_ws;
  float* sinkbuf = partbuf + (size_t)(2 * N) * PSTRIDE;
  emd_gram   <<<dim3(2 * N), dim3(256), 0, stream>>>(support, query, partbuf);
  emd_combine<<<dim3(N),     dim3(256), 0, stream>>>(partbuf, sinkbuf);
  emd_sink   <<<dim3(N),     dim3(64),  0, stream>>>(sinkbuf, out);
}